// Round 13
// baseline (504.081 us; speedup 1.0000x reference)
//
#include <hip/hip_runtime.h>

typedef _Float16 f16x8 __attribute__((ext_vector_type(8)));
typedef _Float16 f16x4 __attribute__((ext_vector_type(4)));
typedef __fp16  fp16x2 __attribute__((ext_vector_type(2)));
typedef float f32x4 __attribute__((ext_vector_type(4)));
typedef unsigned int u32;

#define ROWS 64
#define THREADS 512

// ---------------------------------------------------------------------------
// Prep: W1/W2/W3 (f32 [K][C]) -> f16 fragment-linear WF[ct][kt][lane][8],
// block-diag masks applied by gathering only in-block K.
//   col = ct*16 + (lane&15), k = kbase + kt*32 + (lane>>4)*8 + j
// ---------------------------------------------------------------------------
__global__ __launch_bounds__(512) void pack_weights(
    const float* __restrict__ W1, const float* __restrict__ W2,
    const float* __restrict__ W3, _Float16* __restrict__ WF1,
    _Float16* __restrict__ WF2, _Float16* __restrict__ WF3) {
  int t = blockIdx.x * 512 + threadIdx.x;
  const float* src; _Float16* dst; int idx, ct, kt, lane, kbase;
  if (t < 131072) {                       // W1: 64 ct * 32 kt
    idx = t; src = W1; dst = WF1;
    ct = idx >> 11; kt = (idx >> 6) & 31; lane = idx & 63; kbase = 0;
  } else if (t < 196608) {                // W2: 64 ct * 16 kt
    idx = t - 131072; src = W2; dst = WF2;
    ct = idx >> 10; kt = (idx >> 6) & 15; lane = idx & 63;
    kbase = (ct >= 32) ? 512 : 0;         // 2 blocks of 512
  } else {                                // W3: 64 ct * 8 kt
    idx = t - 196608; src = W3; dst = WF3;
    ct = idx >> 9; kt = (idx >> 6) & 7; lane = idx & 63;
    kbase = (ct >> 4) << 8;               // 4 blocks of 256
  }
  int c  = ct * 16 + (lane & 15);
  int k0 = kbase + kt * 32 + ((lane >> 4) << 3);
  f16x8 v;
#pragma unroll
  for (int j = 0; j < 8; ++j) v[j] = (_Float16)src[(size_t)(k0 + j) * 1024 + c];
  *reinterpret_cast<f16x8*>(dst + (size_t)idx * 8) = v;
}

// ---------------------------------------------------------------------------
// K-loop, TRANSPOSED mfma (D = W_frag * h_frag), 2-kt pipeline on both
// operands (W global->reg dbuf, h ds_read->reg dbuf). No setprio (m190:
// negative on lockstep waves). Row-XOR swizzle uses the FULL 4-bit row
// (row&15)<<4: 16 x 16B slots -> 2 lanes/bank = conflict-free (vs the old
// (row&7)<<4 = 8 slots = 4-way aliasing).
// ---------------------------------------------------------------------------
template <int KTFULL>
__device__ __forceinline__ void kloop(const _Float16* __restrict__ WF, char* hb,
                                      f32x4 (&acc)[4][4], int ct0, int lane,
                                      int nkt, u32 ldsk0) {
  const f16x8* wf = reinterpret_cast<const f16x8*>(WF) +
                    (u32)(ct0 * KTFULL * 64 + lane);
  const int arow = lane & 15;
  const int koff = (lane >> 4) << 3;
  const u32 abase = (u32)(arow * 2048);
  const u32 axor  = (u32)(arow << 4);       // row&15 == arow for all rf

  f16x8 wA[4], wB[4], hA[4], hB[4];
#define LOADW(buf, ktv)                                                        \
  { u32 _kt = (u32)(ktv);                                                      \
    _Pragma("unroll") for (int cf = 0; cf < 4; ++cf)                           \
      buf[cf] = wf[(u32)(cf * KTFULL) * 64u + _kt * 64u]; }
#define LDH(buf, ktv)                                                          \
  { u32 kb = ldsk0 + (u32)((ktv) * 64) + (u32)(koff * 2);                      \
    _Pragma("unroll") for (int rf = 0; rf < 4; ++rf) {                         \
      u32 addr = ((u32)(rf * 32768) + abase + kb) ^ axor;                      \
      buf[rf] = *reinterpret_cast<const f16x8*>(hb + addr);                    \
    } }
#define DOMFMA(w, h)                                                           \
  { _Pragma("unroll") for (int cf = 0; cf < 4; ++cf)                           \
      _Pragma("unroll") for (int rf = 0; rf < 4; ++rf)                         \
        acc[cf][rf] = __builtin_amdgcn_mfma_f32_16x16x32_f16(w[cf], h[rf],     \
                                                             acc[cf][rf], 0, 0, 0); }

  LOADW(wA, 0);
  LDH(hA, 0);
#pragma unroll 1
  for (int kt = 0; kt < nkt; kt += 2) {
    int ktn = (kt + 2 < nkt) ? (kt + 2) : 0;
    LOADW(wB, kt + 1);                    // issue next-kt loads first
    LDH(hB, kt + 1);
    DOMFMA(wA, hA);
    LOADW(wA, ktn);
    LDH(hA, ktn);
    DOMFMA(wB, hB);
  }
#undef LOADW
#undef LDH
#undef DOMFMA
}

// ---------------------------------------------------------------------------
// Fused forward: 64 rows/WG, h in LDS [64][1024] f16 (128 KiB, XOR-swizzled
// with (row&15)<<4). 8 waves; each layer runs TWO col-passes (wave = 64 cols
// x 64 rows, acc=64 AGPR). Pass-1 output parked activated+packed in regs;
// one barrier covers both passes' reads; then both stores.
// ---------------------------------------------------------------------------
__global__
__attribute__((amdgpu_flat_work_group_size(512, 512), amdgpu_waves_per_eu(2, 2)))
void bspinn_fused(
    const float* __restrict__ X, const float* __restrict__ lb,
    const float* __restrict__ ub,
    const float* __restrict__ W0, const float* __restrict__ b0,
    const _Float16* __restrict__ WF1, const float* __restrict__ b1,
    const _Float16* __restrict__ WF2, const float* __restrict__ b2,
    const _Float16* __restrict__ WF3, const float* __restrict__ b3,
    const float* __restrict__ W4, const float* __restrict__ b4,
    float* __restrict__ out) {
  __shared__ alignas(16) char hb[ROWS * 2048];   // 128 KiB
  __shared__ float xs[ROWS * 4];
  __shared__ float partials[8 * ROWS];

  const int tid  = threadIdx.x;
  const int lane = tid & 63;
  const int wid  = tid >> 6;
  const int r0   = blockIdx.x * ROWS;

  if (tid < ROWS * 3) {                      // stage + normalize X
    int r = tid / 3, j = tid - r * 3;
    float x = X[(size_t)r0 * 3 + tid];
    xs[r * 4 + j] = 2.0f * (x - lb[j]) / (ub[j] - lb[j]) - 1.0f;
  }
  __syncthreads();

  // ---- layer 1 (K=3, VALU): each thread owns 2 cols x 64 rows ----
  {
    int c0 = tid * 2;
    float wa0 = W0[c0],        wb0 = W0[c0 + 1];
    float wa1 = W0[1024 + c0], wb1 = W0[1025 + c0];
    float wa2 = W0[2048 + c0], wb2 = W0[2049 + c0];
    float ba = b0[c0], bbv = b0[c0 + 1];
#pragma unroll 4
    for (int r = 0; r < ROWS; ++r) {
      float x0 = xs[r * 4], x1 = xs[r * 4 + 1], x2 = xs[r * 4 + 2];
      float va = __sinf(fmaf(x2, wa2, fmaf(x1, wa1, fmaf(x0, wa0, ba))));
      float vb = __sinf(fmaf(x2, wb2, fmaf(x1, wb1, fmaf(x0, wb0, bbv))));
      union { fp16x2 h2; u32 u; } pk;
      pk.h2 = __builtin_amdgcn_cvt_pkrtz(va, vb);
      u32 addr = ((u32)(r * 2048 + c0 * 2)) ^ ((u32)((r & 15) << 4));
      *reinterpret_cast<u32*>(hb + addr) = pk.u;
    }
  }
  __syncthreads();

  const int csub = (lane >> 4) << 2;
  const int rr   = lane & 15;
  f32x4 acc[4][4];
  f16x4 p1[4][4], p2[4][4];

  auto zacc = [&]() {
#pragma unroll
    for (int cf = 0; cf < 4; ++cf)
#pragma unroll
      for (int rf = 0; rf < 4; ++rf) acc[cf][rf] = f32x4{0.f, 0.f, 0.f, 0.f};
  };
  auto epi_regs = [&](f16x4 (&p)[4][4], const float* bias, int c0w) {
#pragma unroll
    for (int cf = 0; cf < 4; ++cf) {
      int c0 = c0w + cf * 16 + csub;
      f32x4 bb = *reinterpret_cast<const f32x4*>(bias + c0);
#pragma unroll
      for (int rf = 0; rf < 4; ++rf) {
        float s0 = __sinf(acc[cf][rf][0] + bb[0]);
        float s1 = __sinf(acc[cf][rf][1] + bb[1]);
        float s2 = __sinf(acc[cf][rf][2] + bb[2]);
        float s3 = __sinf(acc[cf][rf][3] + bb[3]);
        union { fp16x2 h2[2]; f16x4 v; } pk;
        pk.h2[0] = __builtin_amdgcn_cvt_pkrtz(s0, s1);
        pk.h2[1] = __builtin_amdgcn_cvt_pkrtz(s2, s3);
        p[cf][rf] = pk.v;
      }
    }
  };
  auto store_regs = [&](f16x4 (&p)[4][4], int c0w) {
#pragma unroll
    for (int cf = 0; cf < 4; ++cf) {
      int c0 = c0w + cf * 16 + csub;
#pragma unroll
      for (int rf = 0; rf < 4; ++rf) {
        int r = rf * 16 + rr;                // r&15 == rr
        u32 addr = ((u32)(r * 2048 + c0 * 2)) ^ ((u32)(rr << 4));
        *reinterpret_cast<f16x4*>(hb + addr) = p[cf][rf];
      }
    }
  };

  const int cw0 = wid * 64;                  // pass-0 cols
  const int cw1 = 512 + wid * 64;            // pass-1 cols
  const int ct00 = wid * 4, ct01 = 32 + wid * 4;

  // ---- layer 2 (dense, K=1024) ----
  zacc(); kloop<32>(WF1, hb, acc, ct00, lane, 32, 0);
  epi_regs(p1, b1, cw0);
  zacc(); kloop<32>(WF1, hb, acc, ct01, lane, 32, 0);
  epi_regs(p2, b1, cw1);
  __syncthreads();                           // everyone done reading h1
  store_regs(p1, cw0); store_regs(p2, cw1);
  __syncthreads();                           // h2 ready

  // ---- layer 3 (2 blocks of 512: block = pass) ----
  zacc(); kloop<16>(WF2, hb, acc, ct00, lane, 16, 0);
  epi_regs(p1, b2, cw0);
  zacc(); kloop<16>(WF2, hb, acc, ct01, lane, 16, 1024);
  epi_regs(p2, b2, cw1);
  __syncthreads();
  store_regs(p1, cw0); store_regs(p2, cw1);
  __syncthreads();                           // h3 ready

  // ---- layer 4 (4 blocks of 256: block = pass*2 + (wid>>2)) ----
  {
    u32 k0a = (u32)(((wid >> 2)) * 512);
    u32 k0b = (u32)((2 + (wid >> 2)) * 512);
    zacc(); kloop<8>(WF3, hb, acc, ct00, lane, 8, k0a);
    epi_regs(p1, b3, cw0);
    zacc(); kloop<8>(WF3, hb, acc, ct01, lane, 8, k0b);
    epi_regs(p2, b3, cw1);
    __syncthreads();
    store_regs(p1, cw0); store_regs(p2, cw1);
    __syncthreads();                         // h4 ready
  }

  // ---- layer 5 (M=1, VALU): lane = row, 128 k per wave-segment ----
  {
    int r = lane, seg = wid;
    u32 rb = (u32)(r * 2048);
    u32 xr = (u32)((r & 15) << 4);
    float s = 0.f;
#pragma unroll
    for (int kk = 0; kk < 128; kk += 8) {
      int k = seg * 128 + kk;
      f16x8 v = *reinterpret_cast<const f16x8*>(hb + ((rb + (u32)(k * 2)) ^ xr));
#pragma unroll
      for (int j = 0; j < 8; ++j) s = fmaf((float)v[j], W4[k + j], s);
    }
    partials[seg * 64 + r] = s;
  }
  __syncthreads();
  if (tid < ROWS) {
    float s = b4[0];
#pragma unroll
    for (int g = 0; g < 8; ++g) s += partials[g * 64 + tid];
    out[r0 + tid] = s;
  }
}

extern "C" void kernel_launch(void* const* d_in, const int* in_sizes, int n_in,
                              void* d_out, int out_size, void* d_ws, size_t ws_size,
                              hipStream_t stream) {
  const float* X  = (const float*)d_in[0];
  const float* lb = (const float*)d_in[1];
  const float* ub = (const float*)d_in[2];
  const float* W0 = (const float*)d_in[3];
  const float* b0 = (const float*)d_in[4];
  const float* W1 = (const float*)d_in[5];
  const float* b1 = (const float*)d_in[6];
  const float* W2 = (const float*)d_in[7];
  const float* b2 = (const float*)d_in[8];
  const float* W3 = (const float*)d_in[9];
  const float* b3 = (const float*)d_in[10];
  const float* W4 = (const float*)d_in[11];
  const float* b4 = (const float*)d_in[12];
  float* out = (float*)d_out;

  _Float16* WF1 = (_Float16*)d_ws;                                    // 2 MiB
  _Float16* WF2 = (_Float16*)((char*)d_ws + 2097152);                 // 1 MiB
  _Float16* WF3 = (_Float16*)((char*)d_ws + 3145728);                 // 512 KiB

  hipLaunchKernelGGL(pack_weights, dim3(448), dim3(512), 0, stream,
                     W1, W2, W3, WF1, WF2, WF3);
  hipLaunchKernelGGL(bspinn_fused, dim3(131072 / ROWS), dim3(THREADS), 0, stream,
                     X, lb, ub, W0, b0, WF1, b1, WF2, b2, WF3, b3, W4, b4, out);
}

// Round 14
// 482.603 us; speedup vs baseline: 1.0445x; 1.0445x over previous
//
#include <hip/hip_runtime.h>

typedef _Float16 f16x8 __attribute__((ext_vector_type(8)));
typedef _Float16 f16x4 __attribute__((ext_vector_type(4)));
typedef __fp16  fp16x2 __attribute__((ext_vector_type(2)));
typedef float f32x4 __attribute__((ext_vector_type(4)));
typedef unsigned int u32;

#define N_TOTAL 131072

// ---------------------------------------------------------------------------
// Prep: W1/W2/W3 (f32 [K][C]) -> f16 fragment-linear WF[ct][kt][lane][8],
// block-diag masks applied by gathering only in-block K.
//   col = ct*16 + (lane&15), k = kbase + kt*32 + (lane>>4)*8 + j
// ---------------------------------------------------------------------------
__global__ __launch_bounds__(512) void pack_weights(
    const float* __restrict__ W1, const float* __restrict__ W2,
    const float* __restrict__ W3, _Float16* __restrict__ WF1,
    _Float16* __restrict__ WF2, _Float16* __restrict__ WF3) {
  int t = blockIdx.x * 512 + threadIdx.x;
  const float* src; _Float16* dst; int idx, ct, kt, lane, kbase;
  if (t < 131072) {                       // W1: 64 ct * 32 kt
    idx = t; src = W1; dst = WF1;
    ct = idx >> 11; kt = (idx >> 6) & 31; lane = idx & 63; kbase = 0;
  } else if (t < 196608) {                // W2: 64 ct * 16 kt
    idx = t - 131072; src = W2; dst = WF2;
    ct = idx >> 10; kt = (idx >> 6) & 15; lane = idx & 63;
    kbase = (ct >= 32) ? 512 : 0;         // 2 blocks of 512
  } else {                                // W3: 64 ct * 8 kt
    idx = t - 196608; src = W3; dst = WF3;
    ct = idx >> 9; kt = (idx >> 6) & 7; lane = idx & 63;
    kbase = (ct >> 4) << 8;               // 4 blocks of 256
  }
  int c  = ct * 16 + (lane & 15);
  int k0 = kbase + kt * 32 + ((lane >> 4) << 3);
  f16x8 v;
#pragma unroll
  for (int j = 0; j < 8; ++j) v[j] = (_Float16)src[(size_t)(k0 + j) * 1024 + c];
  *reinterpret_cast<f16x8*>(dst + (size_t)idx * 8) = v;
}

// ---------------------------------------------------------------------------
// K-loop, TRANSPOSED mfma (D = W_frag * h_frag), single-buffered (r7's exact
// no-spill form: fits 128-unified at 4 waves/EU: 64 AGPR acc + ~64 arch).
// Latency cover comes from 2 co-resident WGs (independent barrier domains).
// LDS tile [64][512] f16; full-row swizzle (row&15)<<4 (r13: 6x fewer
// conflicts).
// ---------------------------------------------------------------------------
template <int KTFULL>
__device__ __forceinline__ void kloop(const _Float16* __restrict__ WF, char* hb,
                                      f32x4 (&acc)[4][4], int ct0, int lane,
                                      int nkt, int ktW0, u32 ldsk0) {
  const f16x8* wf = reinterpret_cast<const f16x8*>(WF) +
                    (u32)((ct0 * KTFULL + ktW0) * 64 + lane);
  const int arow = lane & 15;
  const int koff = (lane >> 4) << 3;
  const u32 abase = (u32)(arow * 1024);
  const u32 axor  = (u32)(arow << 4);       // row&15 == arow for all rf

#pragma unroll 1
  for (int kt = 0; kt < nkt; ++kt) {
    f16x8 w[4];
#pragma unroll
    for (int cf = 0; cf < 4; ++cf)
      w[cf] = wf[(u32)(cf * KTFULL) * 64u + (u32)kt * 64u];   // L2 first
    u32 kb = ldsk0 + (u32)(kt * 64) + (u32)(koff * 2);
    f16x8 h[4];
#pragma unroll
    for (int rf = 0; rf < 4; ++rf) {
      u32 addr = ((u32)(rf * 16384) + abase + kb) ^ axor;
      h[rf] = *reinterpret_cast<const f16x8*>(hb + addr);
    }
    __builtin_amdgcn_s_setprio(1);
#pragma unroll
    for (int cf = 0; cf < 4; ++cf)
#pragma unroll
      for (int rf = 0; rf < 4; ++rf)
        acc[cf][rf] = __builtin_amdgcn_mfma_f32_16x16x32_f16(w[cf], h[rf],
                                                             acc[cf][rf], 0, 0, 0);
    __builtin_amdgcn_s_setprio(0);
  }
}

// ---------------------------------------------------------------------------
// Fused forward, column-split, 2 WGs/CU: WG = (64-row tile) x (512-col half).
// h in LDS [64][512] f16 = 64 KiB -> TWO WGs co-resident per CU, independent
// barrier domains (while one WG drains a barrier/epilogue, the other feeds
// the matrix pipe). Layer 1 (K=3) recomputed per WG in two 512-col passes to
// feed layer 2's K=1024 through the same buffer (acc persists in AGPRs).
// Layers 3/4 block-diagonal => self-contained in the half. Layer 5 emits a
// partial dot; reduce_out sums the two halves.
// ---------------------------------------------------------------------------
__global__
__attribute__((amdgpu_flat_work_group_size(512, 512), amdgpu_waves_per_eu(4, 4)))
void bspinn_fused(
    const float* __restrict__ X, const float* __restrict__ lb,
    const float* __restrict__ ub,
    const float* __restrict__ W0, const float* __restrict__ b0,
    const _Float16* __restrict__ WF1, const float* __restrict__ b1,
    const _Float16* __restrict__ WF2, const float* __restrict__ b2,
    const _Float16* __restrict__ WF3, const float* __restrict__ b3,
    const float* __restrict__ W4, float* __restrict__ P) {
  __shared__ alignas(16) char hb[64 * 1024];     // [64 rows][512 f16] = 64 KiB
  __shared__ float xs[64 * 4];
  __shared__ float partials[8 * 64];

  const int tid  = threadIdx.x;
  const int lane = tid & 63;
  const int wid  = tid >> 6;
  const int tile = blockIdx.x >> 1;
  const int half = blockIdx.x & 1;
  const int r0   = tile * 64;

  if (tid < 192) {                           // stage + normalize X (64 rows)
    int r = tid / 3, j = tid - r * 3;
    float x = X[(size_t)r0 * 3 + tid];
    xs[r * 4 + j] = 2.0f * (x - lb[j]) / (ub[j] - lb[j]) - 1.0f;
  }
  __syncthreads();

  // layer 1 (K=3): h1 global cols [cbase, cbase+512) -> LDS local [0,512)
  auto layer1 = [&](int cbase) {
    int c0l = (tid & 255) * 2;               // local col pair
    int rb  = (tid >> 8) * 32;               // row half
    int cg  = cbase + c0l;
    float wa0 = W0[cg],        wb0 = W0[cg + 1];
    float wa1 = W0[1024 + cg], wb1 = W0[1025 + cg];
    float wa2 = W0[2048 + cg], wb2 = W0[2049 + cg];
    float ba = b0[cg], bbv = b0[cg + 1];
#pragma unroll 4
    for (int rr2 = 0; rr2 < 32; ++rr2) {
      int r = rb + rr2;
      float x0 = xs[r * 4], x1 = xs[r * 4 + 1], x2 = xs[r * 4 + 2];
      float va = __sinf(fmaf(x2, wa2, fmaf(x1, wa1, fmaf(x0, wa0, ba))));
      float vb = __sinf(fmaf(x2, wb2, fmaf(x1, wb1, fmaf(x0, wb0, bbv))));
      union { fp16x2 h2; u32 u; } pk;
      pk.h2 = __builtin_amdgcn_cvt_pkrtz(va, vb);
      u32 addr = ((u32)(r * 1024 + c0l * 2)) ^ ((u32)((r & 15) << 4));
      *reinterpret_cast<u32*>(hb + addr) = pk.u;
    }
  };

  const int csub = (lane >> 4) << 2;
  const int rr   = lane & 15;
  const int ct0  = half * 32 + wid * 4;      // global 16-col tile base
  f32x4 acc[4][4];

  auto zacc = [&]() {
#pragma unroll
    for (int cf = 0; cf < 4; ++cf)
#pragma unroll
      for (int rf = 0; rf < 4; ++rf) acc[cf][rf] = f32x4{0.f, 0.f, 0.f, 0.f};
  };
  // h_out = sin(acc + bias) -> LDS local cols (barrier before call ensures
  // all reads of the buffer are done)
  auto epi_store = [&](const float* bias) {
#pragma unroll
    for (int cf = 0; cf < 4; ++cf) {
      int c0l = wid * 64 + cf * 16 + csub;
      int cg  = half * 512 + c0l;
      f32x4 bb = *reinterpret_cast<const f32x4*>(bias + cg);
#pragma unroll
      for (int rf = 0; rf < 4; ++rf) {
        int r = rf * 16 + rr;
        float s0 = __sinf(acc[cf][rf][0] + bb[0]);
        float s1 = __sinf(acc[cf][rf][1] + bb[1]);
        float s2 = __sinf(acc[cf][rf][2] + bb[2]);
        float s3 = __sinf(acc[cf][rf][3] + bb[3]);
        union { fp16x2 h2[2]; f16x4 v; } pk;
        pk.h2[0] = __builtin_amdgcn_cvt_pkrtz(s0, s1);
        pk.h2[1] = __builtin_amdgcn_cvt_pkrtz(s2, s3);
        u32 addr = ((u32)(r * 1024 + c0l * 2)) ^ ((u32)(rr << 4));
        *reinterpret_cast<f16x4*>(hb + addr) = pk.v;
      }
    }
  };

  // ---- layer 1a + layer 2 (dense K=1024 via two K=512 chunks) ----
  layer1(0);
  __syncthreads();                           // h1a visible
  zacc();
  kloop<32>(WF1, hb, acc, ct0, lane, 16, 0, 0);
  __syncthreads();                           // h1a reads done
  layer1(512);
  __syncthreads();                           // h1b visible
  kloop<32>(WF1, hb, acc, ct0, lane, 16, 16, 0);
  __syncthreads();                           // h1b reads done
  epi_store(b1);
  __syncthreads();                           // h2 ready

  // ---- layer 3 (2 blocks of 512: our half == our block) ----
  zacc();
  kloop<16>(WF2, hb, acc, ct0, lane, 16, 0, 0);
  __syncthreads();
  epi_store(b2);
  __syncthreads();                           // h3 ready

  // ---- layer 4 (4 blocks of 256: local k base = (wid>>2)*256) ----
  zacc();
  kloop<8>(WF3, hb, acc, ct0, lane, 8, 0, (u32)((wid >> 2) * 512));
  __syncthreads();
  epi_store(b3);
  __syncthreads();                           // h4 ready

  // ---- layer 5 partial (this half's 512 k): lane = row ----
  {
    int r = lane;
    u32 rb = (u32)(r * 1024);
    u32 xr = (u32)((r & 15) << 4);
    float s = 0.f;
#pragma unroll
    for (int kk = 0; kk < 64; kk += 8) {
      int kl = wid * 64 + kk;
      const float* w4p = W4 + half * 512 + kl;
      f16x8 v = *reinterpret_cast<const f16x8*>(hb + ((rb + (u32)(kl * 2)) ^ xr));
#pragma unroll
      for (int j = 0; j < 8; ++j) s = fmaf((float)v[j], w4p[j], s);
    }
    partials[wid * 64 + r] = s;
  }
  __syncthreads();
  if (tid < 64) {
    float s = 0.f;
#pragma unroll
    for (int g = 0; g < 8; ++g) s += partials[g * 64 + tid];
    P[(size_t)half * N_TOTAL + r0 + tid] = s;
  }
}

__global__ __launch_bounds__(256) void reduce_out(
    const float* __restrict__ P, const float* __restrict__ b4,
    float* __restrict__ out) {
  int i = blockIdx.x * 256 + threadIdx.x;
  out[i] = P[i] + P[N_TOTAL + i] + b4[0];
}

extern "C" void kernel_launch(void* const* d_in, const int* in_sizes, int n_in,
                              void* d_out, int out_size, void* d_ws, size_t ws_size,
                              hipStream_t stream) {
  const float* X  = (const float*)d_in[0];
  const float* lb = (const float*)d_in[1];
  const float* ub = (const float*)d_in[2];
  const float* W0 = (const float*)d_in[3];
  const float* b0 = (const float*)d_in[4];
  const float* W1 = (const float*)d_in[5];
  const float* b1 = (const float*)d_in[6];
  const float* W2 = (const float*)d_in[7];
  const float* b2 = (const float*)d_in[8];
  const float* W3 = (const float*)d_in[9];
  const float* b3 = (const float*)d_in[10];
  const float* W4 = (const float*)d_in[11];
  const float* b4 = (const float*)d_in[12];
  float* out = (float*)d_out;

  _Float16* WF1 = (_Float16*)d_ws;                                    // 2 MiB
  _Float16* WF2 = (_Float16*)((char*)d_ws + 2097152);                 // 1 MiB
  _Float16* WF3 = (_Float16*)((char*)d_ws + 3145728);                 // 512 KiB
  float*    P   = (float*)((char*)d_ws + 3670016);                    // 1 MiB

  hipLaunchKernelGGL(pack_weights, dim3(448), dim3(512), 0, stream,
                     W1, W2, W3, WF1, WF2, WF3);
  hipLaunchKernelGGL(bspinn_fused, dim3((N_TOTAL / 64) * 2), dim3(512), 0, stream,
                     X, lb, ub, W0, b0, WF1, b1, WF2, b2, WF3, b3, W4, P);
  hipLaunchKernelGGL(reduce_out, dim3(N_TOTAL / 256), dim3(256), 0, stream,
                     P, b4, out);
}